// Round 3
// baseline (273.398 us; speedup 1.0000x reference)
//
#include <hip/hip_runtime.h>
#include <hip/hip_cooperative_groups.h>
#include <math.h>

namespace cg = cooperative_groups;

// Problem: B=16, C=128, H=W=64 -> N = 8,388,608 f32 elements.
// Reference collapses analytically:
//   softmax(w).sum(axis=1) == 1   =>  integral(d, param, idx) == param[idx]
//   linspace tables are affine    =>  interplot == a + b*index
//   theta = -pi + 2*pi*sigmoid(d) =>  sin(theta) = -sin(2*pi*sg), cos likewise
//   ds    = e * |tanh(d)|
//   pre   = d*exp(ds*sin th) + ds*cos th
// Global mean/std (ddof=1) normalize of input (x iscale) and of pre (x oscale).
//
// Round-2 lesson: 3 separate kernels re-read the input 3x and pay 3 launch/
// drain boundaries; sum ~114us vs ~10us HBM floor. This version is ONE
// cooperative kernel: every thread holds its 32 elements in VGPRs across two
// grid.sync()s. HBM traffic = 32MB read + 32MB write + 48KB partials.

#define NTOT 8388608
#define NV   (NTOT / 4)          // 2,097,152 float4
#define GA   1024                // blocks (== 4 blocks/CU x 256 CUs, co-resident)
#define TB   256                 // threads per block
#define STRIDE (GA * TB)         // 262,144 threads
#define ITERS  (NV / STRIDE)     // 8 float4 = 32 floats per thread, in registers

__device__ __forceinline__ float fast_rcp(float x) {
    return __builtin_amdgcn_rcpf(x);
}

// x -> pre-normalization output value. m1 = mean(data), k1 = iscale/std(data).
__device__ __forceinline__ float lnon_elem(float x, float m1, float k1) {
    float d  = (x - m1) * k1;
    float a  = fminf(fabsf(d), 30.0f);       // saturation guard
    float Ea = __expf(a);                    // e^{|d|}, shared by sigmoid & tanh
    float sg = (d >= 0.0f ? Ea : 1.0f) * fast_rcp(1.0f + Ea);   // sigmoid(d)
    float t  = 1.0f - 2.0f * fast_rcp(1.0f + Ea * Ea);          // tanh(|d|)
    float dsv = 2.71828182845904523f * t;                       // ds
    // theta = 2*pi*sg - pi; v_sin/cos_f32 take REVOLUTIONS: sin(2*pi*sg).
    float sn = -__builtin_amdgcn_sinf(sg);
    float cs = -__builtin_amdgcn_cosf(sg);
    return fmaf(d, __expf(dsv * sn), dsv * cs);
}

// Reduce a double pair across the 256-thread block; result valid in ALL threads.
__device__ __forceinline__ void block_reduce2(double& s, double& q) {
    #pragma unroll
    for (int off = 32; off > 0; off >>= 1) {
        s += __shfl_down(s, off);
        q += __shfl_down(q, off);
    }
    __shared__ double lds[4][2];
    const int wave = threadIdx.x >> 6;
    const int lane = threadIdx.x & 63;
    __syncthreads();                          // guard LDS reuse across calls
    if (lane == 0) { lds[wave][0] = s; lds[wave][1] = q; }
    __syncthreads();
    s = lds[0][0] + lds[1][0] + lds[2][0] + lds[3][0];
    q = lds[0][1] + lds[1][1] + lds[2][1] + lds[3][1];
}

__device__ __forceinline__ void stats_from(double s, double q, float sc,
                                           float& m, float& k) {
    const double Nd = (double)NTOT;
    double mean = s / Nd;
    double var  = (q - s * s / Nd) / (Nd - 1.0);
    m = (float)mean;
    k = (float)(1.0 / sqrt(var)) * sc;
}

__global__ __launch_bounds__(TB, 4) void k_fused(
        const float4* __restrict__ in,
        const float*  __restrict__ iscale,
        const float*  __restrict__ oscale,
        double2*      __restrict__ P1,
        double2*      __restrict__ P2,
        float4*       __restrict__ out) {
    cg::grid_group grid = cg::this_grid();
    const int t = blockIdx.x * TB + threadIdx.x;

    // ---- Phase A: load entire slice into registers; input sum/sumsq ----
    float4 v[ITERS];
    float sf = 0.0f, qf = 0.0f;
    #pragma unroll
    for (int k = 0; k < ITERS; ++k) {
        v[k] = in[t + k * STRIDE];
        sf += v[k].x + v[k].y + v[k].z + v[k].w;
        qf += v[k].x * v[k].x + v[k].y * v[k].y
            + v[k].z * v[k].z + v[k].w * v[k].w;
    }
    double s1 = (double)sf, q1 = (double)qf;
    block_reduce2(s1, q1);
    if (threadIdx.x == 0) P1[blockIdx.x] = make_double2(s1, q1);
    grid.sync();

    // ---- Phase B: redundant reduce of P1 -> (m1,k1); transform in-place ----
    s1 = 0.0; q1 = 0.0;
    #pragma unroll
    for (int i = threadIdx.x; i < GA; i += TB) {
        double2 p = P1[i];
        s1 += p.x; q1 += p.y;
    }
    block_reduce2(s1, q1);
    float m1, k1;
    stats_from(s1, q1, iscale[0], m1, k1);

    float s2f = 0.0f, q2f = 0.0f;
    #pragma unroll
    for (int k = 0; k < ITERS; ++k) {
        v[k].x = lnon_elem(v[k].x, m1, k1);
        v[k].y = lnon_elem(v[k].y, m1, k1);
        v[k].z = lnon_elem(v[k].z, m1, k1);
        v[k].w = lnon_elem(v[k].w, m1, k1);
        s2f += v[k].x + v[k].y + v[k].z + v[k].w;
        q2f += v[k].x * v[k].x + v[k].y * v[k].y
             + v[k].z * v[k].z + v[k].w * v[k].w;
    }
    double s2 = (double)s2f, q2 = (double)q2f;
    block_reduce2(s2, q2);
    if (threadIdx.x == 0) P2[blockIdx.x] = make_double2(s2, q2);
    grid.sync();

    // ---- Phase C: redundant reduce of P2 -> (m2,k2); normalize + store ----
    s2 = 0.0; q2 = 0.0;
    #pragma unroll
    for (int i = threadIdx.x; i < GA; i += TB) {
        double2 p = P2[i];
        s2 += p.x; q2 += p.y;
    }
    block_reduce2(s2, q2);
    float m2, k2;
    stats_from(s2, q2, oscale[0], m2, k2);

    #pragma unroll
    for (int k = 0; k < ITERS; ++k) {
        float4 o;
        o.x = (v[k].x - m2) * k2;
        o.y = (v[k].y - m2) * k2;
        o.z = (v[k].z - m2) * k2;
        o.w = (v[k].w - m2) * k2;
        out[t + k * STRIDE] = o;
    }
}

extern "C" void kernel_launch(void* const* d_in, const int* in_sizes, int n_in,
                              void* d_out, int out_size, void* d_ws, size_t ws_size,
                              hipStream_t stream) {
    const float4* data   = (const float4*)d_in[0];
    const float*  iscale = (const float*)d_in[1];
    const float*  oscale = (const float*)d_in[2];
    // d_in[3..6] (weight_sp, weight_ch, conv_w, conv_b): mathematically dead
    // (softmax row-sums are identically 1).
    float4*  out = (float4*)d_out;
    double2* P1  = (double2*)d_ws;        // GA entries
    double2* P2  = P1 + GA;               // GA entries (32 KiB total)

    void* args[] = {(void*)&data, (void*)&iscale, (void*)&oscale,
                    (void*)&P1, (void*)&P2, (void*)&out};
    (void)hipLaunchCooperativeKernel((void*)k_fused, dim3(GA), dim3(TB),
                                     args, 0, stream);
}